// Round 6
// baseline (352.819 us; speedup 1.0000x reference)
//
#include <hip/hip_runtime.h>

#define F_IN  128
#define F_HID 64
#define F_OUT 40
#define BSZ   512          // nodes per bucket
#define BSH   9            // log2(BSZ)
#define CAP   24576        // bucket region capacity

// pack two floats as bf16 pair (round-to-nearest-even): low16 = a, high16 = b
static __device__ __forceinline__ unsigned pack_bf16(float a, float b) {
    unsigned ua = __float_as_uint(a);
    unsigned ub = __float_as_uint(b);
    ua = (ua + 0x7fffu + ((ua >> 16) & 1u)) >> 16;
    ub = (ub + 0x7fffu + ((ub >> 16) & 1u)) & 0xffff0000u;
    return ua | ub;
}
static __device__ __forceinline__ float bf_lo(unsigned u) { return __uint_as_float(u << 16); }
static __device__ __forceinline__ float bf_hi(unsigned u) { return __uint_as_float(u & 0xffff0000u); }

// ---------------- partition edges into destination buckets ----------------
__global__ void k_partition(const int* __restrict__ row, const int* __restrict__ col,
                            int E, int nb, int* __restrict__ gcur,
                            unsigned* __restrict__ bbuf) {
    __shared__ int hist[256];
    __shared__ int cur[256];
    int t = threadIdx.x;
    hist[t] = 0;
    __syncthreads();
    int chunk = (E + gridDim.x - 1) / gridDim.x;
    int e0 = blockIdx.x * chunk;
    int e1 = min(E, e0 + chunk);
    for (int e = e0 + t; e < e1; e += 256)
        atomicAdd(&hist[col[e] >> BSH], 1);
    __syncthreads();
    if (t < nb) cur[t] = t * CAP + atomicAdd(&gcur[t], hist[t]);
    __syncthreads();
    for (int e = e0 + t; e < e1; e += 256) {
        int c = col[e];
        int b = c >> BSH;
        int pos = atomicAdd(&cur[b], 1);
        if (pos < (b + 1) * CAP)
            bbuf[pos] = ((unsigned)row[e] << BSH) | (unsigned)(c & (BSZ - 1));
    }
}

// ---------------- per-bucket counting sort -> bucket-relative CSR ----------------
__global__ void __launch_bounds__(1024)
k_csr(const unsigned* __restrict__ bbuf, const int* __restrict__ gcur,
      int* __restrict__ beg, int* __restrict__ deg, float* __restrict__ dinv,
      int* __restrict__ srow, int n) {
    __shared__ unsigned pay[CAP];   // 96 KB
    __shared__ int cnt[BSZ];
    __shared__ int cur[BSZ];
    int b = blockIdx.x, t = threadIdx.x;
    int nE = min(gcur[b], CAP);
    int base = b * CAP;
    for (int i = t; i < BSZ; i += 1024) cnt[i] = 0;
    __syncthreads();
    for (int i = t; i < nE; i += 1024) {
        unsigned u = bbuf[base + i];
        pay[i] = u;
        atomicAdd(&cnt[u & (BSZ - 1)], 1);
    }
    __syncthreads();
    if (t < BSZ) cur[t] = cnt[t];
    __syncthreads();
    for (int off = 1; off < BSZ; off <<= 1) {
        int add = (t < BSZ && t >= off) ? cur[t - off] : 0;
        __syncthreads();
        if (t < BSZ) cur[t] += add;
        __syncthreads();
    }
    int node0 = b * BSZ;
    if (t < BSZ) {
        int ex = cur[t] - cnt[t];
        int node = node0 + t;
        if (node < n) {
            beg[node] = base + ex;
            deg[node] = cnt[t];
            dinv[node] = rsqrtf((float)cnt[t] + 1.0f);
        }
        cur[t] = ex;
    }
    __syncthreads();
    for (int i = t; i < nE; i += 1024) {
        unsigned u = pay[i];
        int pos = atomicAdd(&cur[u & (BSZ - 1)], 1);
        srow[base + pos] = (int)(u >> BSH);
    }
}

// ---------------- layer 1 linear: h1b = bf16( dinv * (x @ W1) ) ----------------
// dword p of a row holds features (2p, 2p+1)
__global__ void k_lin1(const float* __restrict__ x, const float* __restrict__ W1,
                       const float* __restrict__ dinv,
                       unsigned* __restrict__ h1b, int n) {
    __shared__ float Ws[F_IN * F_HID];   // 32 KB
    __shared__ float xs[8][F_IN];        // 4 KB
    int t = threadIdx.x;
    for (int i = t; i < F_IN * F_HID; i += 256) Ws[i] = W1[i];
    int node0 = blockIdx.x * 8;
    for (int i = t; i < 8 * F_IN; i += 256) {
        int nd = node0 + (i >> 7);
        xs[i >> 7][i & 127] = (nd < n) ? x[nd * F_IN + (i & 127)] : 0.f;
    }
    __syncthreads();
    int local = t >> 5;
    int c = t & 31;
    float acc0 = 0.f, acc1 = 0.f;
#pragma unroll 8
    for (int k = 0; k < F_IN; ++k) {
        float xv = xs[local][k];
        acc0 = fmaf(xv, Ws[k * F_HID + 2 * c], acc0);
        acc1 = fmaf(xv, Ws[k * F_HID + 2 * c + 1], acc1);
    }
    int nd = node0 + local;
    if (nd < n) {
        float s = dinv[nd];
        h1b[nd * 32 + c] = pack_bf16(acc0 * s, acc1 * s);
    }
}

// ---------------- layer-1 aggregation (8 edges / VMEM, uint4) + relu + fused W2 GEMM ----------------
// lane = 8*g + c: edge slot g (0..7), row-quarter... c = uint4 index (features 8c..8c+7)
__global__ void k_agg1(const uint4* __restrict__ h1q, const int* __restrict__ beg,
                       const int* __restrict__ deg, const int* __restrict__ srow,
                       const float* __restrict__ dinv, const float* __restrict__ b1,
                       const float* __restrict__ W2, unsigned* __restrict__ h2b, int n) {
    __shared__ float W2s[F_HID * F_OUT];  // 10 KB
    __shared__ float b1s[F_HID];
    __shared__ float zrow[4][F_HID];
    int t = threadIdx.x;
    for (int i = t; i < F_HID * F_OUT; i += 256) W2s[i] = W2[i];
    if (t < F_HID) b1s[t] = b1[t];
    __syncthreads();
    int lane = t & 63, w = t >> 6;
    int g = lane >> 3, c = lane & 7;
    int node = blockIdx.x * 4 + w;
    if (node >= n) return;
    int bg = beg[node], cnt = deg[node];
    float a0=0.f,a1=0.f,a2=0.f,a3=0.f,a4=0.f,a5=0.f,a6=0.f,a7=0.f;
    for (int e0 = 0; e0 < cnt; e0 += 64) {
        int m = min(64, cnt - e0);
        int r = (e0 + lane < cnt) ? srow[bg + e0 + lane] : 0;
        for (int j = 0; j < m; j += 8) {
            int idx = j + g;
            int rr = __shfl(r, min(idx, m - 1));
            uint4 u = h1q[rr * 8 + c];
            if (idx < m) {
                a0 += bf_lo(u.x); a1 += bf_hi(u.x);
                a2 += bf_lo(u.y); a3 += bf_hi(u.y);
                a4 += bf_lo(u.z); a5 += bf_hi(u.z);
                a6 += bf_lo(u.w); a7 += bf_hi(u.w);
            }
        }
    }
    // reduce across the 8 edge-slot groups
#pragma unroll
    for (int off = 8; off <= 32; off <<= 1) {
        a0 += __shfl_xor(a0, off); a1 += __shfl_xor(a1, off);
        a2 += __shfl_xor(a2, off); a3 += __shfl_xor(a3, off);
        a4 += __shfl_xor(a4, off); a5 += __shfl_xor(a5, off);
        a6 += __shfl_xor(a6, off); a7 += __shfl_xor(a7, off);
    }
    float dv = dinv[node];
    if (g == 0) {
        uint4 us = h1q[node * 8 + c];   // self-loop (already dinv-scaled)
        a0 += bf_lo(us.x); a1 += bf_hi(us.x);
        a2 += bf_lo(us.y); a3 += bf_hi(us.y);
        a4 += bf_lo(us.z); a5 += bf_hi(us.z);
        a6 += bf_lo(us.w); a7 += bf_hi(us.w);
        float z;
        z = fmaf(a0, dv, b1s[8*c+0]); zrow[w][8*c+0] = z > 0.f ? z : 0.f;
        z = fmaf(a1, dv, b1s[8*c+1]); zrow[w][8*c+1] = z > 0.f ? z : 0.f;
        z = fmaf(a2, dv, b1s[8*c+2]); zrow[w][8*c+2] = z > 0.f ? z : 0.f;
        z = fmaf(a3, dv, b1s[8*c+3]); zrow[w][8*c+3] = z > 0.f ? z : 0.f;
        z = fmaf(a4, dv, b1s[8*c+4]); zrow[w][8*c+4] = z > 0.f ? z : 0.f;
        z = fmaf(a5, dv, b1s[8*c+5]); zrow[w][8*c+5] = z > 0.f ? z : 0.f;
        z = fmaf(a6, dv, b1s[8*c+6]); zrow[w][8*c+6] = z > 0.f ? z : 0.f;
        z = fmaf(a7, dv, b1s[8*c+7]); zrow[w][8*c+7] = z > 0.f ? z : 0.f;
    }
    // same-wave DS write->read, in-order DS pipe
    float s = 0.f;
    if (lane < F_OUT) {
#pragma unroll
        for (int k = 0; k < F_HID; ++k)
            s = fmaf(zrow[w][k], W2s[k * F_OUT + lane], s);
        s *= dv;
    }
    float partner = __shfl_xor(s, 1);
    if (lane < F_OUT && (lane & 1) == 0)
        h2b[node * 20 + (lane >> 1)] = pack_bf16(s, partner);
}

// ---------------- layer-2 aggregation (4 edges / VMEM, uint2) + bias + log_softmax ----------------
// lane = 16*g + c: edge slot g (0..3), uint2 index c (features 4c..4c+3), active c<10
__global__ void k_agg2(const uint2* __restrict__ h2q, const int* __restrict__ beg,
                       const int* __restrict__ deg, const int* __restrict__ srow,
                       const float* __restrict__ dinv, const float* __restrict__ b2,
                       float* __restrict__ out, int n) {
    int t = threadIdx.x, lane = t & 63, w = t >> 6;
    int g = lane >> 4, c = lane & 15;
    int cc = min(c, 9);
    bool act = c < 10;
    int node = blockIdx.x * 4 + w;
    if (node >= n) return;
    int bg = beg[node], cnt = deg[node];
    float a0=0.f,a1=0.f,a2=0.f,a3=0.f;
    for (int e0 = 0; e0 < cnt; e0 += 64) {
        int m = min(64, cnt - e0);
        int r = (e0 + lane < cnt) ? srow[bg + e0 + lane] : 0;
        for (int j = 0; j < m; j += 4) {
            int idx = j + g;
            int rr = __shfl(r, min(idx, m - 1));
            uint2 u = h2q[rr * 10 + cc];
            if (idx < m && act) {
                a0 += bf_lo(u.x); a1 += bf_hi(u.x);
                a2 += bf_lo(u.y); a3 += bf_hi(u.y);
            }
        }
    }
    a0 += __shfl_xor(a0, 16); a1 += __shfl_xor(a1, 16);
    a2 += __shfl_xor(a2, 16); a3 += __shfl_xor(a3, 16);
    a0 += __shfl_xor(a0, 32); a1 += __shfl_xor(a1, 32);
    a2 += __shfl_xor(a2, 32); a3 += __shfl_xor(a3, 32);
    float dv = dinv[node];
    if (g == 0 && act) {
        uint2 us = h2q[node * 10 + cc];   // self-loop
        a0 += bf_lo(us.x); a1 += bf_hi(us.x);
        a2 += bf_lo(us.y); a3 += bf_hi(us.y);
    }
    float v0 = act ? fmaf(a0, dv, b2[4*cc+0]) : -1e30f;
    float v1 = act ? fmaf(a1, dv, b2[4*cc+1]) : -1e30f;
    float v2 = act ? fmaf(a2, dv, b2[4*cc+2]) : -1e30f;
    float v3 = act ? fmaf(a3, dv, b2[4*cc+3]) : -1e30f;
    // softmax over 40 classes held in lanes 0..9 of each 16-lane group (use g==0)
    float mx = fmaxf(fmaxf(v0, v1), fmaxf(v2, v3));
#pragma unroll
    for (int off = 1; off <= 8; off <<= 1) mx = fmaxf(mx, __shfl_xor(mx, off));
    float ex = act ? (expf(v0 - mx) + expf(v1 - mx) + expf(v2 - mx) + expf(v3 - mx)) : 0.f;
#pragma unroll
    for (int off = 1; off <= 8; off <<= 1) ex += __shfl_xor(ex, off);
    float lg = logf(ex);
    if (g == 0 && act) {
        float4 o;
        o.x = v0 - mx - lg; o.y = v1 - mx - lg;
        o.z = v2 - mx - lg; o.w = v3 - mx - lg;
        *reinterpret_cast<float4*>(&out[node * F_OUT + 4 * c]) = o;
    }
}

extern "C" void kernel_launch(void* const* d_in, const int* in_sizes, int n_in,
                              void* d_out, int out_size, void* d_ws, size_t ws_size,
                              hipStream_t stream) {
    const float* x  = (const float*)d_in[0];
    const int*   ei = (const int*)d_in[1];
    const float* W1 = (const float*)d_in[2];
    const float* b1 = (const float*)d_in[3];
    const float* W2 = (const float*)d_in[4];
    const float* b2 = (const float*)d_in[5];
    float* out = (float*)d_out;

    const int n = in_sizes[0] / F_IN;
    const int E = in_sizes[1] / 2;
    const int* row = ei;
    const int* col = ei + E;
    const int nb = (n + BSZ - 1) / BSZ;

    char* p = (char*)d_ws;
    float*    dinv = (float*)p;     p += (size_t)n * 4;
    unsigned* h1b  = (unsigned*)p;  p += (size_t)n * 32 * 4;
    unsigned* h2b  = (unsigned*)p;  p += (size_t)n * 20 * 4;
    int*      beg  = (int*)p;       p += (size_t)n * 4;
    int*      deg  = (int*)p;       p += (size_t)n * 4;
    int*      gcur = (int*)p;       p += 256 * 4;
    unsigned* bbuf = (unsigned*)p;  p += (size_t)nb * CAP * 4;
    int*      srow = (int*)p;       p += (size_t)nb * CAP * 4;

    hipMemsetAsync(gcur, 0, nb * 4, stream);
    k_partition<<<640, 256, 0, stream>>>(row, col, E, nb, gcur, bbuf);
    k_csr<<<nb, 1024, 0, stream>>>(bbuf, gcur, beg, deg, dinv, srow, n);
    k_lin1<<<(n + 7) / 8, 256, 0, stream>>>(x, W1, dinv, h1b, n);
    k_agg1<<<(n + 3) / 4, 256, 0, stream>>>((const uint4*)h1b, beg, deg, srow, dinv, b1, W2, h2b, n);
    k_agg2<<<(n + 3) / 4, 256, 0, stream>>>((const uint2*)h2b, beg, deg, srow, dinv, b2, out, n);
}